// Round 2
// baseline (84.609 us; speedup 1.0000x reference)
//
#include <hip/hip_runtime.h>
#include <math.h>

static constexpr int Bn = 64, Mn = 50, Cn = 4;
static constexpr int CORR_BLOCKS = 64;       // one per batch image
static constexpr int BASE_BLOCKS = 2048;
static constexpr int TOTAL_BLOCKS = CORR_BLOCKS + BASE_BLOCKS;

#define LOG2E 1.4426950408889634f
#define LN2   0.6931471805599453f

// ws float layout:
//  0..2  : focal base sums per scale (t=0 over all cls elements)
//  3..5  : obj base sums per scale   (t=0 over all obj elements)
//  6..8  : cls corrections (focal(x,1)-focal(x,0) at unique (label,cell))
//  9..11 : obj corrections (1.5*sp(-x)-sp(x) at unique cell)
// 12..14 : reg sums (smooth_l1 at unique cell, last-box-wins targets)
// 15..17 : denom (4 per unique cell)
// 18     : block completion counter (as unsigned)

__device__ __forceinline__ float frcp (float x){ return __builtin_amdgcn_rcpf(x); }
__device__ __forceinline__ float fexp2(float x){ return __builtin_amdgcn_exp2f(x); }
__device__ __forceinline__ float flog2(float x){ return __builtin_amdgcn_logf(x); }

__device__ __forceinline__ float focal0_4(float4 v) {
  float s = 0.f;
  const float* px = &v.x;
#pragma unroll
  for (int k = 0; k < 4; ++k) {
    float x = px[k];
    float e   = fexp2(-LOG2E * fabsf(x));   // exp(-|x|)
    float ope = 1.f + e;
    float u   = frcp(ope);                  // sigmoid(|x|)
    float sp  = fmaxf(x, 0.f) + LN2 * flog2(ope);  // softplus(x)
    float p   = (x >= 0.f) ? u : (1.f - u); // sigmoid(x)
    s = fmaf(0.75f * p * p, sp, s);         // focal(x, t=0)
  }
  return s;
}

__device__ __forceinline__ float obj0_4(float4 v) {
  float s = 0.f;
  const float* px = &v.x;
#pragma unroll
  for (int k = 0; k < 4; ++k) {
    float x = px[k];
    float e = fexp2(-LOG2E * fabsf(x));
    s += fmaxf(x, 0.f) + LN2 * flog2(1.f + e);     // softplus(x)
  }
  return s;
}

__device__ __forceinline__ float wave_reduce(float v) {
#pragma unroll
  for (int off = 32; off > 0; off >>= 1) v += __shfl_down(v, off, 64);
  return v;
}

__global__ __launch_bounds__(256) void fused_kernel(
    const float* __restrict__ cls3, const float* __restrict__ reg3, const float* __restrict__ obj3,
    const float* __restrict__ cls4, const float* __restrict__ reg4, const float* __restrict__ obj4,
    const float* __restrict__ cls5, const float* __restrict__ reg5, const float* __restrict__ obj5,
    const float* __restrict__ boxes, const int* __restrict__ labels, const int* __restrict__ valid,
    float* __restrict__ ws, float* __restrict__ out) {
  __shared__ float sdata[6][4];
  __shared__ int s_cell[Mn];
  __shared__ int s_lab[Mn];

  if (blockIdx.x < CORR_BLOCKS) {
    // ---------------- sparse correction path: one block per batch image ----
    int b = blockIdx.x;
    int m = threadIdx.x;

    float x1 = 0.f, y1 = 0.f, x2 = 0.f, y2 = 0.f;
    int lab = 0, val = 0;
    if (m < Mn) {
      const float* bp = boxes + ((size_t)b * Mn + m) * 4;
      x1 = bp[0]; y1 = bp[1]; x2 = bp[2]; y2 = bp[3];
      lab = labels[b * Mn + m];
      val = valid[b * Mn + m];
      s_lab[m] = lab;
    }

    for (int s = 0; s < 3; ++s) {
      const int W = (s == 0) ? 160 : ((s == 1) ? 80 : 40);
      const int H = W;
      const float stride = (s == 0) ? 8.f : ((s == 1) ? 16.f : 32.f);
      const float* clsP = (s == 0) ? cls3 : ((s == 1) ? cls4 : cls5);
      const float* regP = (s == 0) ? reg3 : ((s == 1) ? reg4 : reg5);
      const float* objP = (s == 0) ? obj3 : ((s == 1) ? obj4 : obj5);

      float cx = 0.f, cy = 0.f;
      int gx = 0, gy = 0, cell = -1;
      if (m < Mn && val > 0) {
        cx = (x1 + x2) * 0.5f / stride;
        cy = (y1 + y2) * 0.5f / stride;
        gx = min(max((int)cx, 0), W - 1);
        gy = min(max((int)cy, 0), H - 1);
        cell = gy * W + gx;
      }
      if (m < Mn) s_cell[m] = cell;
      __syncthreads();

      if (cell >= 0) {
        bool firstObj = true, lastReg = true, firstCls = true;
        for (int j = 0; j < Mn; ++j) {
          if (j == m) continue;
          if (s_cell[j] != cell) continue;
          if (j < m) {
            firstObj = false;
            if (s_lab[j] == lab) firstCls = false;
          } else {
            lastReg = false;   // a later valid box overwrites reg targets
          }
        }
        size_t plane = (size_t)H * W;
        size_t pix = (size_t)gy * W + gx;

        if (firstObj) {
          float x = objP[(size_t)b * plane + pix];
          float e = fexp2(-LOG2E * fabsf(x));
          float sp = fmaxf(x, 0.f) + LN2 * flog2(1.f + e);  // softplus(x)
          float corr = 0.5f * sp - 1.5f * x;                // 1.5*sp(-x) - sp(x)
          atomicAdd(&ws[9 + s], corr);
          atomicAdd(&ws[15 + s], 4.0f);                     // denom: 4 ch per cell
        }
        if (firstCls) {
          float x = clsP[((size_t)b * Cn + lab) * plane + pix];
          float e = fexp2(-LOG2E * fabsf(x));
          float ope = 1.f + e;
          float u = frcp(ope);
          float sp = fmaxf(x, 0.f) + LN2 * flog2(ope);
          float spn = sp - x;                               // softplus(-x)
          float p = (x >= 0.f) ? u : (1.f - u);
          float q = 1.f - p;
          float corr = 0.25f * q * q * spn - 0.75f * p * p * sp;
          atomicAdd(&ws[6 + s], corr);
        }
        if (lastReg) {
          float w = fmaxf(x2 - x1, 1.f), h = fmaxf(y2 - y1, 1.f);
          float inv_s = 1.f / stride;
          float t0 = cx - (float)gx, t1 = cy - (float)gy;
          float t2 = LN2 * flog2(w * inv_s), t3 = LN2 * flog2(h * inv_s);
          const float* rp = regP + (size_t)b * 4 * plane + pix;
          float sum = 0.f, d, a;
          d = rp[0]         - t0; a = fabsf(d); sum += (a < 1.f) ? 0.5f * d * d : a - 0.5f;
          d = rp[plane]     - t1; a = fabsf(d); sum += (a < 1.f) ? 0.5f * d * d : a - 0.5f;
          d = rp[2 * plane] - t2; a = fabsf(d); sum += (a < 1.f) ? 0.5f * d * d : a - 0.5f;
          d = rp[3 * plane] - t3; a = fabsf(d); sum += (a < 1.f) ? 0.5f * d * d : a - 0.5f;
          atomicAdd(&ws[12 + s], sum);
        }
      }
      __syncthreads();
    }
  } else {
    // ---------------- dense base path: focal(x,0) + softplus(x) sums -------
    constexpr unsigned N_C3 = Bn * Cn * 160u * 160u / 4;  // float4 counts
    constexpr unsigned N_C4 = Bn * Cn * 80u * 80u / 4;
    constexpr unsigned N_C5 = Bn * Cn * 40u * 40u / 4;
    constexpr unsigned N_O3 = Bn * 160u * 160u / 4;
    constexpr unsigned N_O4 = Bn * 80u * 80u / 4;
    constexpr unsigned N_O5 = Bn * 40u * 40u / 4;

    const float4* c3 = (const float4*)cls3; const float4* c4 = (const float4*)cls4;
    const float4* c5 = (const float4*)cls5; const float4* o3 = (const float4*)obj3;
    const float4* o4 = (const float4*)obj4; const float4* o5 = (const float4*)obj5;

    unsigned gid = (blockIdx.x - CORR_BLOCKS) * blockDim.x + threadIdx.x;
    constexpr unsigned gs = BASE_BLOCKS * 256u;

    float a0 = 0.f, a1 = 0.f, a2 = 0.f, a3 = 0.f, a4 = 0.f, a5 = 0.f;
    for (unsigned i = gid; i < N_C3; i += gs) a0 += focal0_4(c3[i]);
    for (unsigned i = gid; i < N_C4; i += gs) a1 += focal0_4(c4[i]);
    for (unsigned i = gid; i < N_C5; i += gs) a2 += focal0_4(c5[i]);
    for (unsigned i = gid; i < N_O3; i += gs) a3 += obj0_4(o3[i]);
    for (unsigned i = gid; i < N_O4; i += gs) a4 += obj0_4(o4[i]);
    for (unsigned i = gid; i < N_O5; i += gs) a5 += obj0_4(o5[i]);

    a0 = wave_reduce(a0); a1 = wave_reduce(a1); a2 = wave_reduce(a2);
    a3 = wave_reduce(a3); a4 = wave_reduce(a4); a5 = wave_reduce(a5);

    int lane = threadIdx.x & 63;
    int wid = threadIdx.x >> 6;
    if (lane == 0) {
      sdata[0][wid] = a0; sdata[1][wid] = a1; sdata[2][wid] = a2;
      sdata[3][wid] = a3; sdata[4][wid] = a4; sdata[5][wid] = a5;
    }
    __syncthreads();
    if (threadIdx.x < 6) {
      float s = sdata[threadIdx.x][0] + sdata[threadIdx.x][1] +
                sdata[threadIdx.x][2] + sdata[threadIdx.x][3];
      atomicAdd(&ws[threadIdx.x], s);
    }
  }

  // ---------------- completion counter + inline finalize --------------------
  __syncthreads();   // drains this block's outstanding atomics (vmcnt) too
  if (threadIdx.x == 0) {
    __threadfence();
    unsigned old = atomicAdd((unsigned*)&ws[18], 1u);
    if (old == (unsigned)(TOTAL_BLOCKS - 1)) {
      __threadfence();
      const float cls_cnt[3] = {6553600.f, 1638400.f, 409600.f};
      const float obj_cnt[3] = {1638400.f, 409600.f, 102400.f};
      float w[18];
#pragma unroll
      for (int i = 0; i < 18; ++i) w[i] = atomicAdd(&ws[i], 0.f);  // coherent read
      float tc = 0.f, to = 0.f, tr = 0.f;
#pragma unroll
      for (int s = 0; s < 3; ++s) {
        tc += (w[s] + w[6 + s]) / cls_cnt[s];
        to += (w[3 + s] + w[9 + s]) / obj_cnt[s];
        float den = w[15 + s];
        if (den > 0.f) tr += w[12 + s] / fmaxf(den, 1.f);
      }
      float total = 2.5f * tc + 5.0f * tr + 0.5f * to;
      out[0] = total; out[1] = tc; out[2] = tr; out[3] = to;
    }
  }
}

extern "C" void kernel_launch(void* const* d_in, const int* in_sizes, int n_in,
                              void* d_out, int out_size, void* d_ws, size_t ws_size,
                              hipStream_t stream) {
  const float* cls3 = (const float*)d_in[0];
  const float* reg3 = (const float*)d_in[1];
  const float* obj3 = (const float*)d_in[2];
  const float* cls4 = (const float*)d_in[3];
  const float* reg4 = (const float*)d_in[4];
  const float* obj4 = (const float*)d_in[5];
  const float* cls5 = (const float*)d_in[6];
  const float* reg5 = (const float*)d_in[7];
  const float* obj5 = (const float*)d_in[8];
  const float* boxes = (const float*)d_in[9];
  const int* labels = (const int*)d_in[10];
  const int* valid = (const int*)d_in[11];
  float* ws = (float*)d_ws;
  float* out = (float*)d_out;

  hipMemsetAsync(d_ws, 0, 20 * sizeof(float), stream);

  fused_kernel<<<TOTAL_BLOCKS, 256, 0, stream>>>(
      cls3, reg3, obj3, cls4, reg4, obj4, cls5, reg5, obj5,
      boxes, labels, valid, ws, out);
}

// Round 3
// 43.100 us; speedup vs baseline: 1.9631x; 1.9631x over previous
//
#include <hip/hip_runtime.h>
#include <math.h>

static constexpr int Bn = 64, Mn = 50, Cn = 4;
static constexpr int CORR_BLOCKS = 64;       // one per batch image
static constexpr int BASE_BLOCKS = 2048;     // 2048*4 waves = 8 waves/SIMD exactly
static constexpr int TOTAL_BLOCKS = CORR_BLOCKS + BASE_BLOCKS;

// ws float layout (all plain stores, no atomics, fully rewritten every call):
//  [k*2048 + bid]          k=0..5, bid=0..2047 : base partials
//                          k 0..2 = focal(t=0) sums per scale, 3..5 = obj softplus sums
//  [12288 + j*64 + b]      j=0..11, b=0..63    : corr partials per batch image
//                          j 0..2 cls corr, 3..5 obj corr, 6..8 reg sum, 9..11 denom
static constexpr int CORR_OFF = 6 * BASE_BLOCKS;   // 12288

#define LOG2E 1.4426950408889634f
#define LN2   0.6931471805599453f

__device__ __forceinline__ float frcp (float x){ return __builtin_amdgcn_rcpf(x); }
__device__ __forceinline__ float fexp2(float x){ return __builtin_amdgcn_exp2f(x); }
__device__ __forceinline__ float flog2(float x){ return __builtin_amdgcn_logf(x); }

__device__ __forceinline__ float focal0_4(float4 v) {
  float s = 0.f;
  const float* px = &v.x;
#pragma unroll
  for (int k = 0; k < 4; ++k) {
    float x = px[k];
    float e   = fexp2(-LOG2E * fabsf(x));          // exp(-|x|)
    float ope = 1.f + e;
    float u   = frcp(ope);                          // sigmoid(|x|)
    float sp  = fmaxf(x, 0.f) + LN2 * flog2(ope);   // softplus(x)
    float p   = (x >= 0.f) ? u : (1.f - u);         // sigmoid(x)
    s = fmaf(0.75f * p * p, sp, s);                 // focal(x, t=0)
  }
  return s;
}

__device__ __forceinline__ float obj0_4(float4 v) {
  float s = 0.f;
  const float* px = &v.x;
#pragma unroll
  for (int k = 0; k < 4; ++k) {
    float x = px[k];
    float e = fexp2(-LOG2E * fabsf(x));
    s += fmaxf(x, 0.f) + LN2 * flog2(1.f + e);      // softplus(x)
  }
  return s;
}

__device__ __forceinline__ float wave_reduce(float v) {
#pragma unroll
  for (int off = 32; off > 0; off >>= 1) v += __shfl_down(v, off, 64);
  return v;
}

__global__ __launch_bounds__(256) void main_kernel(
    const float* __restrict__ cls3, const float* __restrict__ reg3, const float* __restrict__ obj3,
    const float* __restrict__ cls4, const float* __restrict__ reg4, const float* __restrict__ obj4,
    const float* __restrict__ cls5, const float* __restrict__ reg5, const float* __restrict__ obj5,
    const float* __restrict__ boxes, const int* __restrict__ labels, const int* __restrict__ valid,
    float* __restrict__ ws) {
  if (blockIdx.x < CORR_BLOCKS) {
    // ---------------- sparse correction path: one block per batch image ----
    __shared__ int s_cell[Mn];
    __shared__ int s_lab[Mn];
    __shared__ float cacc[12];

    int b = blockIdx.x;
    int m = threadIdx.x;
    if (m < 12) cacc[m] = 0.f;

    float x1 = 0.f, y1 = 0.f, x2 = 0.f, y2 = 0.f;
    int lab = 0, val = 0;
    if (m < Mn) {
      const float* bp = boxes + ((size_t)b * Mn + m) * 4;
      x1 = bp[0]; y1 = bp[1]; x2 = bp[2]; y2 = bp[3];
      lab = labels[b * Mn + m];
      val = valid[b * Mn + m];
      s_lab[m] = lab;
    }

    for (int s = 0; s < 3; ++s) {
      const int W = (s == 0) ? 160 : ((s == 1) ? 80 : 40);
      const int H = W;
      const float stride = (s == 0) ? 8.f : ((s == 1) ? 16.f : 32.f);
      const float* clsP = (s == 0) ? cls3 : ((s == 1) ? cls4 : cls5);
      const float* regP = (s == 0) ? reg3 : ((s == 1) ? reg4 : reg5);
      const float* objP = (s == 0) ? obj3 : ((s == 1) ? obj4 : obj5);

      float cx = 0.f, cy = 0.f;
      int gx = 0, gy = 0, cell = -1;
      if (m < Mn && val > 0) {
        cx = (x1 + x2) * 0.5f / stride;
        cy = (y1 + y2) * 0.5f / stride;
        gx = min(max((int)cx, 0), W - 1);
        gy = min(max((int)cy, 0), H - 1);
        cell = gy * W + gx;
      }
      if (m < Mn) s_cell[m] = cell;
      __syncthreads();

      if (cell >= 0) {
        bool firstObj = true, lastReg = true, firstCls = true;
        for (int j = 0; j < Mn; ++j) {
          if (j == m) continue;
          if (s_cell[j] != cell) continue;
          if (j < m) {
            firstObj = false;
            if (s_lab[j] == lab) firstCls = false;
          } else {
            lastReg = false;   // a later valid box overwrites reg targets
          }
        }
        size_t plane = (size_t)H * W;
        size_t pix = (size_t)gy * W + gx;

        if (firstObj) {
          float x = objP[(size_t)b * plane + pix];
          float e = fexp2(-LOG2E * fabsf(x));
          float sp = fmaxf(x, 0.f) + LN2 * flog2(1.f + e);  // softplus(x)
          float corr = 0.5f * sp - 1.5f * x;                // 1.5*sp(-x) - sp(x)
          atomicAdd(&cacc[3 + s], corr);
          atomicAdd(&cacc[9 + s], 4.0f);                    // denom: 4 ch per cell
        }
        if (firstCls) {
          float x = clsP[((size_t)b * Cn + lab) * plane + pix];
          float e = fexp2(-LOG2E * fabsf(x));
          float ope = 1.f + e;
          float u = frcp(ope);
          float sp = fmaxf(x, 0.f) + LN2 * flog2(ope);
          float spn = sp - x;                               // softplus(-x)
          float p = (x >= 0.f) ? u : (1.f - u);
          float q = 1.f - p;
          float corr = 0.25f * q * q * spn - 0.75f * p * p * sp;
          atomicAdd(&cacc[0 + s], corr);
        }
        if (lastReg) {
          float w = fmaxf(x2 - x1, 1.f), h = fmaxf(y2 - y1, 1.f);
          float inv_s = 1.f / stride;
          float t0 = cx - (float)gx, t1 = cy - (float)gy;
          float t2 = LN2 * flog2(w * inv_s), t3 = LN2 * flog2(h * inv_s);
          const float* rp = regP + (size_t)b * 4 * plane + pix;
          float sum = 0.f, d, a;
          d = rp[0]         - t0; a = fabsf(d); sum += (a < 1.f) ? 0.5f * d * d : a - 0.5f;
          d = rp[plane]     - t1; a = fabsf(d); sum += (a < 1.f) ? 0.5f * d * d : a - 0.5f;
          d = rp[2 * plane] - t2; a = fabsf(d); sum += (a < 1.f) ? 0.5f * d * d : a - 0.5f;
          d = rp[3 * plane] - t3; a = fabsf(d); sum += (a < 1.f) ? 0.5f * d * d : a - 0.5f;
          atomicAdd(&cacc[6 + s], sum);
        }
      }
      __syncthreads();
    }

    if (m < 12) ws[CORR_OFF + m * 64 + b] = cacc[m];   // private slot, plain store
  } else {
    // ---------------- dense base path: focal(x,0) + softplus(x) sums -------
    __shared__ float sdata[6][4];
    constexpr unsigned N_C3 = Bn * Cn * 160u * 160u / 4;  // float4 counts
    constexpr unsigned N_C4 = Bn * Cn * 80u * 80u / 4;
    constexpr unsigned N_C5 = Bn * Cn * 40u * 40u / 4;
    constexpr unsigned N_O3 = Bn * 160u * 160u / 4;
    constexpr unsigned N_O4 = Bn * 80u * 80u / 4;
    constexpr unsigned N_O5 = Bn * 40u * 40u / 4;

    const float4* c3 = (const float4*)cls3; const float4* c4 = (const float4*)cls4;
    const float4* c5 = (const float4*)cls5; const float4* o3 = (const float4*)obj3;
    const float4* o4 = (const float4*)obj4; const float4* o5 = (const float4*)obj5;

    const unsigned baseBid = blockIdx.x - CORR_BLOCKS;
    unsigned gid = baseBid * blockDim.x + threadIdx.x;
    constexpr unsigned gs = BASE_BLOCKS * 256u;

    float a0 = 0.f, a1 = 0.f, a2 = 0.f, a3 = 0.f, a4 = 0.f, a5 = 0.f;
    for (unsigned i = gid; i < N_C3; i += gs) a0 += focal0_4(c3[i]);
    for (unsigned i = gid; i < N_C4; i += gs) a1 += focal0_4(c4[i]);
    for (unsigned i = gid; i < N_C5; i += gs) a2 += focal0_4(c5[i]);
    for (unsigned i = gid; i < N_O3; i += gs) a3 += obj0_4(o3[i]);
    for (unsigned i = gid; i < N_O4; i += gs) a4 += obj0_4(o4[i]);
    for (unsigned i = gid; i < N_O5; i += gs) a5 += obj0_4(o5[i]);

    a0 = wave_reduce(a0); a1 = wave_reduce(a1); a2 = wave_reduce(a2);
    a3 = wave_reduce(a3); a4 = wave_reduce(a4); a5 = wave_reduce(a5);

    int lane = threadIdx.x & 63;
    int wid = threadIdx.x >> 6;
    if (lane == 0) {
      sdata[0][wid] = a0; sdata[1][wid] = a1; sdata[2][wid] = a2;
      sdata[3][wid] = a3; sdata[4][wid] = a4; sdata[5][wid] = a5;
    }
    __syncthreads();
    if (threadIdx.x < 6) {
      float s = sdata[threadIdx.x][0] + sdata[threadIdx.x][1] +
                sdata[threadIdx.x][2] + sdata[threadIdx.x][3];
      ws[threadIdx.x * BASE_BLOCKS + baseBid] = s;   // private slot, plain store
    }
  }
}

__global__ __launch_bounds__(256) void finalize_kernel(
    const float* __restrict__ ws, float* __restrict__ out) {
  __shared__ float sdata[6][4];
  __shared__ float res[18];
  const int t = threadIdx.x;
  const int lane = t & 63;
  const int wid = t >> 6;

  // reduce the 6 base columns (2048 partials each, coalesced)
#pragma unroll
  for (int k = 0; k < 6; ++k) {
    float s = 0.f;
#pragma unroll
    for (int j = 0; j < BASE_BLOCKS / 256; ++j) s += ws[k * BASE_BLOCKS + t + j * 256];
    s = wave_reduce(s);
    if (lane == 0) sdata[k][wid] = s;
  }
  __syncthreads();
  if (t < 6) res[t] = sdata[t][0] + sdata[t][1] + sdata[t][2] + sdata[t][3];

  // reduce the 12 corr rows (64 partials each) on wave 0
  if (wid == 0) {
#pragma unroll
    for (int j = 0; j < 12; ++j) {
      float v = ws[CORR_OFF + j * 64 + lane];
      v = wave_reduce(v);
      if (lane == 0) res[6 + j] = v;
    }
  }
  __syncthreads();

  if (t == 0) {
    const float cls_cnt[3] = {6553600.f, 1638400.f, 409600.f};
    const float obj_cnt[3] = {1638400.f, 409600.f, 102400.f};
    float tc = 0.f, to = 0.f, tr = 0.f;
#pragma unroll
    for (int s = 0; s < 3; ++s) {
      tc += (res[s] + res[6 + s]) / cls_cnt[s];        // base + cls corr
      to += (res[3 + s] + res[9 + s]) / obj_cnt[s];    // base + obj corr
      float den = res[15 + s];
      if (den > 0.f) tr += res[12 + s] / fmaxf(den, 1.f);
    }
    float total = 2.5f * tc + 5.0f * tr + 0.5f * to;
    out[0] = total; out[1] = tc; out[2] = tr; out[3] = to;
  }
}

extern "C" void kernel_launch(void* const* d_in, const int* in_sizes, int n_in,
                              void* d_out, int out_size, void* d_ws, size_t ws_size,
                              hipStream_t stream) {
  const float* cls3 = (const float*)d_in[0];
  const float* reg3 = (const float*)d_in[1];
  const float* obj3 = (const float*)d_in[2];
  const float* cls4 = (const float*)d_in[3];
  const float* reg4 = (const float*)d_in[4];
  const float* obj4 = (const float*)d_in[5];
  const float* cls5 = (const float*)d_in[6];
  const float* reg5 = (const float*)d_in[7];
  const float* obj5 = (const float*)d_in[8];
  const float* boxes = (const float*)d_in[9];
  const int* labels = (const int*)d_in[10];
  const int* valid = (const int*)d_in[11];
  float* ws = (float*)d_ws;
  float* out = (float*)d_out;

  main_kernel<<<TOTAL_BLOCKS, 256, 0, stream>>>(
      cls3, reg3, obj3, cls4, reg4, obj4, cls5, reg5, obj5,
      boxes, labels, valid, ws);

  finalize_kernel<<<1, 256, 0, stream>>>(ws, out);
}